// Round 1
// baseline (626.919 us; speedup 1.0000x reference)
//
#include <hip/hip_runtime.h>
#include <hip/hip_bf16.h>

// Swin block, MI355X. v1: correctness-first full pipeline, bf16 MFMA GEMMs.
// B=32 H=W=64 C=192 WS=8 SS=4 NH=6 Dh=32 N=64 nW=64; T = B*H*W = 131072 tokens.

#define DI __device__ __forceinline__

typedef __attribute__((ext_vector_type(8))) short bhalf8;   // 8 bf16 (4 VGPR)
typedef __attribute__((ext_vector_type(4))) float f32x4;
typedef unsigned short u16;
typedef unsigned int   u32;

DI u16 f2bf(float f){                       // RNE f32->bf16
  union { float f; u32 u; } v; v.f = f;
  u32 r = v.u + 0x7FFFu + ((v.u >> 16) & 1u);
  return (u16)(r >> 16);
}
DI float bf2f(u16 b){ union { u32 u; float f; } v; v.u = ((u32)b) << 16; return v.f; }

static const int T_TOK = 131072;

// dest window-token index t -> source/dest global token g (shift+partition map;
// identical for LN1 gather and proj scatter since roll/unroll use the same offset)
DI int tok2glob(int t){
  int n = t & 63, widx = t >> 6;
  int b = widx >> 6, wi = widx & 63;
  int hh = ((wi >> 3) << 3) + (n >> 3);
  int ww = ((wi & 7) << 3) + (n & 7);
  int hs = (hh + 4) & 63, wsv = (ww + 4) & 63;
  return (b << 12) + (hs << 6) + wsv;
}

// ---------------- LN kernel (1 wave / token; 192 = 64 lanes * 3) ----------------
template<int PERM>
__global__ __launch_bounds__(256) void ln_kernel(const float* __restrict__ src,
    const float* __restrict__ gam, const float* __restrict__ bet, u16* __restrict__ dst){
  int wid = threadIdx.x >> 6, lane = threadIdx.x & 63;
  int t = blockIdx.x * 4 + wid;
  int gsrc = PERM ? tok2glob(t) : t;
  const float* xr = src + (size_t)gsrc * 192;
  int c = lane * 3;
  float v0 = xr[c], v1 = xr[c+1], v2 = xr[c+2];
  float s = v0+v1+v2, sq = v0*v0+v1*v1+v2*v2;
  #pragma unroll
  for (int d = 1; d < 64; d <<= 1){ s += __shfl_xor(s, d, 64); sq += __shfl_xor(sq, d, 64); }
  float mean = s * (1.f/192.f);
  float var  = sq * (1.f/192.f) - mean*mean;
  float rstd = rsqrtf(var + 1e-5f);
  u16* dr = dst + (size_t)t * 192;
  dr[c]   = f2bf((v0-mean)*rstd*gam[c]  + bet[c]);
  dr[c+1] = f2bf((v1-mean)*rstd*gam[c+1]+ bet[c+1]);
  dr[c+2] = f2bf((v2-mean)*rstd*gam[c+2]+ bet[c+2]);
}

// ------------- weight prep: W(K,N) fp32 -> Wt(N,K) bf16 -------------
__global__ void transcast_kernel(const float* __restrict__ W, u16* __restrict__ Wt, int K, int N){
  int idx = blockIdx.x * 256 + threadIdx.x;
  if (idx < K*N){
    int n = idx / K, k = idx - n*K;
    Wt[idx] = f2bf(W[(size_t)k * N + n]);
  }
}

// ---------------- GEMM: C(M,N) = A(M,K) * Wt(N,K)^T, tile 128x64, BK=64 ----------------
// EPI 0: qkv  -> outH bf16, +bias, ldo=576
// EPI 1: proj -> outF fp32 scattered: out[g] = res[g] + bias + acc   (xmid)
// EPI 2: fc1  -> outH bf16 = gelu(acc+bias), ldo=768
// EPI 3: fc2  -> outF fp32: out[row] = res[row] + bias + acc  (res==outF alias ok)
template<int EPI>
__global__ __launch_bounds__(256) void gemm_kernel(
    const u16* __restrict__ A, const u16* __restrict__ Bt,
    const float* __restrict__ bias, const float* res,
    float* outF, u16* __restrict__ outH, int K, int ldo){
  __shared__ u16 As[128*64];
  __shared__ u16 Bs[64*64];
  int mBase = blockIdx.x * 128;
  int nBase = blockIdx.y * 64;
  int tid = threadIdx.x;
  int lane = tid & 63, w = tid >> 6;
  int wr = w >> 1, wc = w & 1;
  int lr = lane & 15, lg = lane >> 4;
  f32x4 acc[4][2];
  #pragma unroll
  for (int i=0;i<4;i++)
    #pragma unroll
    for (int n=0;n<2;n++) acc[i][n] = (f32x4){0.f,0.f,0.f,0.f};

  int nsteps = K >> 6;
  int r0 = tid >> 3;
  int ko = (tid & 7) << 3;
  for (int kb = 0; kb < nsteps; kb++){
    int kOff = kb << 6;
    #pragma unroll
    for (int it = 0; it < 4; it++){           // A tile 128x64
      int row = r0 + it*32;
      const u16* gp = A + (size_t)(mBase + row) * K + kOff + ko;
      int kidx = ko ^ ((row & 7) << 3);
      *(uint4*)&As[row*64 + kidx] = *(const uint4*)gp;
    }
    #pragma unroll
    for (int it = 0; it < 2; it++){           // B tile 64x64 (already transposed)
      int n = r0 + it*32;
      const u16* gp = Bt + (size_t)(nBase + n) * K + kOff + ko;
      int kidx = ko ^ ((n & 7) << 3);
      *(uint4*)&Bs[n*64 + kidx] = *(const uint4*)gp;
    }
    __syncthreads();
    #pragma unroll
    for (int kk = 0; kk < 2; kk++){
      bhalf8 aF[4], bF[2];
      #pragma unroll
      for (int i=0;i<4;i++){
        int row = wr*64 + i*16 + lr;
        int kidx = ((kk<<5) + (lg<<3)) ^ ((row&7)<<3);
        aF[i] = *(const bhalf8*)&As[row*64 + kidx];
      }
      #pragma unroll
      for (int n=0;n<2;n++){
        int col = wc*32 + n*16 + lr;
        int kidx = ((kk<<5) + (lg<<3)) ^ ((col&7)<<3);
        bF[n] = *(const bhalf8*)&Bs[col*64 + kidx];
      }
      #pragma unroll
      for (int i=0;i<4;i++)
        #pragma unroll
        for (int n=0;n<2;n++)
          acc[i][n] = __builtin_amdgcn_mfma_f32_16x16x32_bf16(aF[i], bF[n], acc[i][n], 0, 0, 0);
    }
    __syncthreads();
  }
  #pragma unroll
  for (int i=0;i<4;i++){
    #pragma unroll
    for (int n=0;n<2;n++){
      int col = nBase + wc*32 + n*16 + lr;
      float bv = bias[col];
      #pragma unroll
      for (int r=0;r<4;r++){
        int row = mBase + wr*64 + i*16 + lg*4 + r;
        float v = acc[i][n][r] + bv;
        if (EPI == 0){
          outH[(size_t)row * ldo + col] = f2bf(v);
        } else if (EPI == 2){
          float gl = 0.5f * v * (1.0f + erff(v * 0.70710678118654752f));
          outH[(size_t)row * ldo + col] = f2bf(gl);
        } else if (EPI == 1){
          int g = tok2glob(row);
          size_t o = (size_t)g * 192 + col;
          outF[o] = res[o] + v;
        } else {
          size_t o = (size_t)row * 192 + col;
          outF[o] = res[o] + v;
        }
      }
    }
  }
}

// ---------------- windowed attention: 1 block/window, 1 wave/head ----------------
DI int region_id(int hpos, int wpos){
  int rh = (hpos < 56) ? 0 : ((hpos < 60) ? 1 : 2);
  int rw = (wpos < 56) ? 0 : ((wpos < 60) ? 1 : 2);
  return rh*3 + rw;
}

__global__ __launch_bounds__(384) void attn_kernel(const u16* __restrict__ QKV,
    u16* __restrict__ CTX, const float* __restrict__ rpb){
  __shared__ u16 Plds[6][64*64];   // P, XOR-swizzled 8-granules
  __shared__ u16 Vt[6][32*64];     // V^T, XOR-swizzled
  __shared__ float Rlds[225*6];
  int widx = blockIdx.x;
  int h = threadIdx.x >> 6, lane = threadIdx.x & 63;
  int lr = lane & 15, lg = lane >> 4;

  for (int i = threadIdx.x; i < 225*6; i += 384) Rlds[i] = rpb[i];

  { // stage V transposed: lane = token, 64B per lane
    const uint4* vp4 = (const uint4*)(QKV + (size_t)(widx*64 + lane)*576 + 384 + h*32);
    #pragma unroll
    for (int q4 = 0; q4 < 4; q4++){
      union { uint4 v; u16 s[8]; } u; u.v = vp4[q4];
      #pragma unroll
      for (int j = 0; j < 8; j++){
        int d = q4*8 + j;
        Vt[h][d*64 + (lane ^ ((d & 7) << 3))] = u.s[j];
      }
    }
  }

  bhalf8 qf[4], kf[4];
  #pragma unroll
  for (int i=0;i<4;i++){
    int row = i*16 + lr;
    qf[i] = *(const bhalf8*)(QKV + (size_t)(widx*64 + row)*576 + h*32 + (lg<<3));
  }
  #pragma unroll
  for (int j=0;j<4;j++){
    int col = j*16 + lr;
    kf[j] = *(const bhalf8*)(QKV + (size_t)(widx*64 + col)*576 + 192 + h*32 + (lg<<3));
  }
  f32x4 sc[4][4];
  f32x4 zero = (f32x4){0.f,0.f,0.f,0.f};
  #pragma unroll
  for (int i=0;i<4;i++)
    #pragma unroll
    for (int j=0;j<4;j++)
      sc[i][j] = __builtin_amdgcn_mfma_f32_16x16x32_bf16(qf[i], kf[j], zero, 0, 0, 0);

  __syncthreads();   // Rlds ready

  int mwin = widx >> 5;                 // faithful to reference reshape quirk
  int mh0 = (mwin >> 3) << 3, mw0 = (mwin & 7) << 3;
  #pragma unroll
  for (int i=0;i<4;i++){
    #pragma unroll
    for (int r=0;r<4;r++){
      int row = i*16 + lg*4 + r;
      int ih = row >> 3, iw = row & 7;
      int ridr = region_id(mh0 + ih, mw0 + iw);
      float vals[4];
      #pragma unroll
      for (int j=0;j<4;j++){
        int col = j*16 + lr;
        int jh = col >> 3, jw = col & 7;
        float bias = Rlds[((ih-jh+7)*15 + (iw-jw+7))*6 + h];
        int ridc = region_id(mh0 + jh, mw0 + jw);
        vals[j] = sc[i][j][r] * 0.17677669529663687f + bias + ((ridr==ridc) ? 0.f : -100.f);
      }
      float mx = fmaxf(fmaxf(vals[0],vals[1]), fmaxf(vals[2],vals[3]));
      #pragma unroll
      for (int d=1; d<16; d<<=1) mx = fmaxf(mx, __shfl_xor(mx, d, 64));
      float sum = 0.f;
      #pragma unroll
      for (int j=0;j<4;j++){ vals[j] = expf(vals[j]-mx); sum += vals[j]; }
      #pragma unroll
      for (int d=1; d<16; d<<=1) sum += __shfl_xor(sum, d, 64);
      float inv = 1.f / sum;
      #pragma unroll
      for (int j=0;j<4;j++){
        int col = j*16 + lr;
        Plds[h][row*64 + (col ^ ((row & 7) << 3))] = f2bf(vals[j]*inv);
      }
    }
  }
  __syncthreads();   // P + V^T ready

  f32x4 oa[4][2];
  #pragma unroll
  for (int i=0;i<4;i++)
    #pragma unroll
    for (int n=0;n<2;n++) oa[i][n] = zero;
  #pragma unroll
  for (int kb=0; kb<2; kb++){
    bhalf8 pf[4], vf[2];
    int k = (kb<<5) + (lg<<3);
    #pragma unroll
    for (int i=0;i<4;i++){
      int row = i*16 + lr;
      pf[i] = *(const bhalf8*)&Plds[h][row*64 + (k ^ ((row&7)<<3))];
    }
    #pragma unroll
    for (int n=0;n<2;n++){
      int d = n*16 + lr;
      vf[n] = *(const bhalf8*)&Vt[h][d*64 + (k ^ ((d&7)<<3))];
    }
    #pragma unroll
    for (int i=0;i<4;i++)
      #pragma unroll
      for (int n=0;n<2;n++)
        oa[i][n] = __builtin_amdgcn_mfma_f32_16x16x32_bf16(pf[i], vf[n], oa[i][n], 0, 0, 0);
  }
  #pragma unroll
  for (int i=0;i<4;i++)
    #pragma unroll
    for (int n=0;n<2;n++)
      #pragma unroll
      for (int r=0;r<4;r++){
        int row = i*16 + lg*4 + r;
        int col = n*16 + lr;
        CTX[(size_t)(widx*64+row)*192 + h*32 + col] = f2bf(oa[i][n][r]);
      }
}

extern "C" void kernel_launch(void* const* d_in, const int* in_sizes, int n_in,
                              void* d_out, int out_size, void* d_ws, size_t ws_size,
                              hipStream_t stream){
  const float* x      = (const float*)d_in[0];
  const float* n1g    = (const float*)d_in[1];
  const float* n1b    = (const float*)d_in[2];
  const float* qkv_w  = (const float*)d_in[3];
  const float* qkv_b  = (const float*)d_in[4];
  const float* proj_w = (const float*)d_in[5];
  const float* proj_b = (const float*)d_in[6];
  const float* rpb    = (const float*)d_in[7];
  const float* n2g    = (const float*)d_in[8];
  const float* n2b    = (const float*)d_in[9];
  const float* fc1_w  = (const float*)d_in[10];
  const float* fc1_b  = (const float*)d_in[11];
  const float* fc2_w  = (const float*)d_in[12];
  const float* fc2_b  = (const float*)d_in[13];
  float* out = (float*)d_out;

  const size_t T = (size_t)T_TOK;
  u16* A    = (u16*)d_ws;            // T*192  (A then A2)
  u16* QKV  = A + T*192;             // region T*768 (QKV then H1)
  u16* H1   = QKV;
  u16* CTX  = QKV + T*768;           // T*192
  u16* WT   = CTX + T*192;
  u16* qkvWt  = WT;
  u16* projWt = qkvWt + 576*192;
  u16* fc1Wt  = projWt + 192*192;
  u16* fc2Wt  = fc1Wt + 768*192;

  transcast_kernel<<<dim3((192*576+255)/256),256,0,stream>>>(qkv_w, qkvWt, 192, 576);
  transcast_kernel<<<dim3((192*192+255)/256),256,0,stream>>>(proj_w, projWt, 192, 192);
  transcast_kernel<<<dim3((192*768+255)/256),256,0,stream>>>(fc1_w, fc1Wt, 192, 768);
  transcast_kernel<<<dim3((768*192+255)/256),256,0,stream>>>(fc2_w, fc2Wt, 768, 192);

  ln_kernel<1><<<dim3(32768),256,0,stream>>>(x, n1g, n1b, A);
  gemm_kernel<0><<<dim3(1024,9),256,0,stream>>>(A, qkvWt, qkv_b, nullptr, nullptr, QKV, 192, 576);
  attn_kernel<<<dim3(2048),384,0,stream>>>(QKV, CTX, rpb);
  gemm_kernel<1><<<dim3(1024,3),256,0,stream>>>(CTX, projWt, proj_b, x, out, nullptr, 192, 192);
  ln_kernel<0><<<dim3(32768),256,0,stream>>>(out, n2g, n2b, A);
  gemm_kernel<2><<<dim3(1024,12),256,0,stream>>>(A, fc1Wt, fc1_b, nullptr, nullptr, H1, 192, 768);
  gemm_kernel<3><<<dim3(1024,3),256,0,stream>>>(H1, fc2Wt, fc2_b, out, out, nullptr, 768, 192);
}